// Round 3
// baseline (101.771 us; speedup 1.0000x reference)
//
#include <hip/hip_runtime.h>
#include <hip/hip_bf16.h>

// out[row] = dot(link[row*128 .. +128], theta[0..128)) for row in [0, 1M)
// Memory-bound: 537 MB read / 4 MB write per call. Strategy: 32 lanes x float4
// per row (fully coalesced), 2 independent row-pairs per wave per iteration
// (2x memory-level parallelism), shfl_xor reduce, nontemporal load/store
// (pure stream, no reuse). Uses clang native vector type for the
// nontemporal builtins (HIP float4 class is rejected).

typedef float f32x4 __attribute__((ext_vector_type(4)));

__global__ __launch_bounds__(256) void linmodel_dot_kernel(
    const float* __restrict__ link,
    const float* __restrict__ theta,
    float* __restrict__ out,
    int num_rows)
{
    const int lane = threadIdx.x & 63;
    const int sub  = lane & 31;   // k-chunk index within row (float4 granularity)
    const int half = lane >> 5;   // which row of the pair this half-wave handles

    const int waveInBlock   = threadIdx.x >> 6;
    const int wavesPerBlock = blockDim.x >> 6;
    const int gwave  = blockIdx.x * wavesPerBlock + waveInBlock;
    const int nwaves = gridDim.x * wavesPerBlock;

    // theta is 128 floats; this lane always dots against chunk `sub`.
    const f32x4 th = reinterpret_cast<const f32x4*>(theta)[sub];

    const f32x4* __restrict__ link4 = reinterpret_cast<const f32x4*>(link);

    // 4 rows per wave per iteration (two independent pairs).
    const int num_quads = num_rows >> 2;

    for (int quad = gwave; quad < num_quads; quad += nwaves) {
        const size_t row0 = (size_t)quad * 4 + half;       // rows quad*4 + {0,1}
        const size_t row1 = row0 + 2;                      // rows quad*4 + {2,3}

        // Two independent 16B loads -> 2 loads in flight per wave.
        const f32x4 a0 = __builtin_nontemporal_load(&link4[row0 * 32 + sub]);
        const f32x4 a1 = __builtin_nontemporal_load(&link4[row1 * 32 + sub]);

        float p0 = a0.x * th.x + a0.y * th.y + a0.z * th.z + a0.w * th.w;
        float p1 = a1.x * th.x + a1.y * th.y + a1.z * th.z + a1.w * th.w;

        // Reduce across the 32 lanes of each half-wave (bits 0..4 only).
        // Two chains are independent; scheduler interleaves them.
        p0 += __shfl_xor(p0, 1);
        p1 += __shfl_xor(p1, 1);
        p0 += __shfl_xor(p0, 2);
        p1 += __shfl_xor(p1, 2);
        p0 += __shfl_xor(p0, 4);
        p1 += __shfl_xor(p1, 4);
        p0 += __shfl_xor(p0, 8);
        p1 += __shfl_xor(p1, 8);
        p0 += __shfl_xor(p0, 16);
        p1 += __shfl_xor(p1, 16);

        if (sub == 0) {
            __builtin_nontemporal_store(p0, &out[row0]);
            __builtin_nontemporal_store(p1, &out[row1]);
        }
    }
}

extern "C" void kernel_launch(void* const* d_in, const int* in_sizes, int n_in,
                              void* d_out, int out_size, void* d_ws, size_t ws_size,
                              hipStream_t stream) {
    const float* link  = (const float*)d_in[0];   // (1024, 1024, 128) f32
    // d_in[1]: route_features — unused by the forward pass
    const float* theta = (const float*)d_in[2];   // (128,) f32
    float* out = (float*)d_out;                   // (1024, 1024) f32

    const int num_rows = out_size;                // 1024*1024

    const int block = 256;
    const int grid  = 2048;  // 8192 waves, grid-stride over 262144 row-quads
    linmodel_dot_kernel<<<grid, block, 0, stream>>>(link, theta, out, num_rows);
}